// Round 10
// baseline (333.616 us; speedup 1.0000x reference)
//
#include <hip/hip_runtime.h>
#include <hip/hip_fp16.h>

#define TEMP 8.0f
#define MSHIFT 8.0f   // constant softmax shift; scores in [0,8) so exp in (e^-8, 1]
#define KDIM 8
#define BKT_SHIFT 6                 // 64 nodes per dst-bucket
#define BKT_NODES (1 << BKT_SHIFT)
#define MAXNB 2048                  // bucket arrays (N <= 131072)
#define TILE 6144                   // edges per partition tile (LDS-sorted)
#define PTHR 512
#define EPT 12                      // TILE / PTHR
#define EPB_H 8192                  // edges per histogram block
#define CAPB 3008                   // fine-pass LDS out-buffer entries (mean 2046, +21sd)
// Evidence ledger (r3-r9):
//  - padding/table-splits/LLC-fit/NT: all NO effect. r7 non-staged partition:
//    REGRESSED (both passes still 1 random store/edge).
//  - r8 L2-resident gather table: agg_half still slow -> random-line cost is
//    NOT DRAM-side; L2 hits occupy the same per-CU outstanding-request slots.
//  - r9 4-slot MLP in agg: -20us (164->145). Partial: per-wave ILP helps until
//    the per-CU slot pool saturates.
//  - MODEL: ~33G random-line-requests/s device-wide (slots x latency).
//    Time ~ line-ops/33G. Scatter 2/edge + agg 1.25/edge ~ 10.4M ~ 315us. FIX =
//    remove line-ops: LDS-staged tile sort (runs of ~4 entries -> full-line
//    stores) + LDS fine scatter (dense CSR payload, streamed out).

__device__ __forceinline__ unsigned pack_h2(float a, float b) {
    __half2 h = __floats2half2_rn(a, b);
    return __builtin_bit_cast(unsigned, h);
}
__device__ __forceinline__ float2 unpack_h2(unsigned v) {
    __half2 h = __builtin_bit_cast(__half2, v);
    return __half22float2(h);
}

__device__ __forceinline__ unsigned long long pack_ql(float4 q, float l) {
    int lu = __float2int_rn(l * 4095.0f);
    lu = lu < 0 ? 0 : (lu > 4095 ? 4095 : lu);
    int vw = __float2int_rn(q.x * 4095.0f);
    int vx = __float2int_rn(q.y * 4095.0f);
    int vy = __float2int_rn(q.z * 4095.0f);
    int vz = __float2int_rn(q.w * 4095.0f);
    return (unsigned long long)(unsigned)lu
         | ((unsigned long long)((unsigned)vw & 0x1FFFu) << 12)
         | ((unsigned long long)((unsigned)vx & 0x1FFFu) << 25)
         | ((unsigned long long)((unsigned)vy & 0x1FFFu) << 38)
         | ((unsigned long long)((unsigned)vz & 0x1FFFu) << 51);
}

__device__ __forceinline__ int sext13(unsigned v) {
    return ((int)(v << 19)) >> 19;
}

// ===== K1: blocks [0,gN) build qltab; blocks [gN,..) LDS-histogram buckets =====
__global__ void prep_hist(const float* __restrict__ levels,
                          const float4* __restrict__ node_q,
                          unsigned long long* __restrict__ qltab, int NK, int gN,
                          const int* __restrict__ edst,
                          int* __restrict__ ghist, int E) {
    __shared__ int h[MAXNB];
    if ((int)blockIdx.x < gN) {
        int i = blockIdx.x * blockDim.x + threadIdx.x;
        if (i >= NK) return;
        qltab[i] = pack_ql(node_q[i], levels[i]);
    } else {
        int tid = threadIdx.x;
        for (int i = tid; i < MAXNB; i += 256) h[i] = 0;
        __syncthreads();
        int beg = (blockIdx.x - gN) * EPB_H;
        int end = beg + EPB_H; if (end > E) end = E;
        for (int e = beg + tid; e < end; e += 256)
            atomicAdd(&h[edst[e] >> BKT_SHIFT], 1);
        __syncthreads();
        for (int i = tid; i < MAXNB; i += 256)
            if (h[i]) atomicAdd(&ghist[i], h[i]);   // non-returning, L2-hot
    }
}

// ===== K2: exclusive scan of bucket counts (1 block, 1024 thr, 2 chunks) =====
__global__ void scan_buckets(const int* __restrict__ ghist,
                             int* __restrict__ gbase,
                             int* __restrict__ gcursor, int NBKT, int E) {
    __shared__ int s[1024];
    __shared__ int carry_s;
    int tid = threadIdx.x;
    if (tid == 0) carry_s = 0;
    __syncthreads();
    for (int base = 0; base < MAXNB; base += 1024) {
        int idx = base + tid;
        int v = (idx < NBKT) ? ghist[idx] : 0;
        s[tid] = v;
        __syncthreads();
        for (int off = 1; off < 1024; off <<= 1) {
            int t = (tid >= off) ? s[tid - off] : 0;
            __syncthreads();
            s[tid] += t;
            __syncthreads();
        }
        if (idx < NBKT) {
            int b = s[tid] - v + carry_s;
            gbase[idx] = b;
            gcursor[idx] = b;
        }
        __syncthreads();
        if (tid == 0) carry_s += s[1023];
        __syncthreads();
    }
    if (tid == 0) gbase[NBKT] = E;
}

// ===== K3: LDS tile-sort partition: sort 6144 edges by bucket in LDS, flush
// bucket-runs (mean ~4 x 16B = full lines) to ebuf via one cursor atomic/run =====
__global__ void __launch_bounds__(PTHR, 1)
partition_lds(const int* __restrict__ edst,
              const int* __restrict__ esrc,
              const float* __restrict__ ew,
              const float4* __restrict__ rel_q,
              int* __restrict__ gcursor,
              float4* __restrict__ ebuf,
              unsigned char* __restrict__ dib, int E) {
    __shared__ float4 sortbuf[TILE];          // 96 KB
    __shared__ unsigned char sdib[TILE];      // 6 KB
    __shared__ int cnt[MAXNB];                // 8 KB
    __shared__ int base[MAXNB];               // 8 KB
    __shared__ int ts[PTHR];                  // 2 KB

    int tid = threadIdx.x;
    int tbeg = blockIdx.x * TILE;

    for (int i = tid; i < MAXNB; i += PTHR) cnt[i] = 0;
    __syncthreads();

    // phase 1: count, remember (bucket, rank, dib) per edge
    int eb[EPT]; int er[EPT]; unsigned char ed[EPT]; bool ev[EPT];
#pragma unroll
    for (int i = 0; i < EPT; ++i) {
        int e = tbeg + i * PTHR + tid;
        ev[i] = (e < E);
        if (ev[i]) {
            int d = edst[e];
            eb[i] = d >> BKT_SHIFT;
            ed[i] = (unsigned char)(d & (BKT_NODES - 1));
            er[i] = atomicAdd(&cnt[eb[i]], 1);
        }
    }
    __syncthreads();

    // phase 2: exclusive scan of cnt -> base (4 buckets/thread + block scan)
    int loc = 0;
#pragma unroll
    for (int j = 0; j < 4; ++j) {
        int b = tid * 4 + j;
        base[b] = loc;
        loc += cnt[b];
    }
    ts[tid] = loc;
    __syncthreads();
    for (int off = 1; off < PTHR; off <<= 1) {
        int t = (tid >= off) ? ts[tid - off] : 0;
        __syncthreads();
        ts[tid] += t;
        __syncthreads();
    }
    int tb = ts[tid] - loc;   // exclusive thread base
#pragma unroll
    for (int j = 0; j < 4; ++j) base[tid * 4 + j] += tb;
    __syncthreads();

    // phase 3: build records, scatter into LDS (bucket-sorted)
#pragma unroll
    for (int i = 0; i < EPT; ++i) {
        if (ev[i]) {
            int e = tbeg + i * PTHR + tid;
            float4 rq = rel_q[e];
            uint4 u;
            u.x = pack_h2(rq.x, rq.y);
            u.y = pack_h2(rq.z, rq.w);
            u.z = __builtin_bit_cast(unsigned, TEMP * ew[e]);
            u.w = (unsigned)(esrc[e] * KDIM);
            int pos = base[eb[i]] + er[i];
            sortbuf[pos] = __builtin_bit_cast(float4, u);
            sdib[pos] = ed[i];
        }
    }
    __syncthreads();

    // phase 4: flush bucket-runs contiguously (one cursor atomic per run)
    for (int b = tid; b < MAXNB; b += PTHR) {
        int c = cnt[b];
        if (c) {
            int gb = atomicAdd(&gcursor[b], c);
            int off = base[b];
            for (int j = 0; j < c; ++j) {
                ebuf[gb + j] = sortbuf[off + j];   // consecutive 16B -> merged lines
                dib[gb + j] = sdib[off + j];
            }
        }
    }
}

// ===== K4: fine scatter inside LDS, one block per bucket; stream out dense
// CSR payload + exact deg/offs =====
__global__ void fine_lds(const int* __restrict__ gbase,
                         const float4* __restrict__ ebuf,
                         const unsigned char* __restrict__ dib,
                         float4* __restrict__ payload,
                         int* __restrict__ deg,
                         int* __restrict__ offs, int N) {
    __shared__ float4 outbuf[CAPB];           // 48 KB
    __shared__ int h[BKT_NODES];
    __shared__ int hx[BKT_NODES];
    __shared__ int c[BKT_NODES];
    int bk = blockIdx.x;
    int tid = threadIdx.x;
    int beg = gbase[bk], end = gbase[bk + 1];
    int cnt = end - beg;

    if (tid < BKT_NODES) { h[tid] = 0; c[tid] = 0; }
    __syncthreads();
    for (int s = beg + tid; s < end; s += 256)
        atomicAdd(&h[dib[s]], 1);
    __syncthreads();
    // exclusive scan of h[64]
    if (tid < BKT_NODES) hx[tid] = h[tid];
    __syncthreads();
    for (int off = 1; off < BKT_NODES; off <<= 1) {
        int t = (tid >= off && tid < BKT_NODES) ? hx[tid - off] : 0;
        __syncthreads();
        if (tid < BKT_NODES) hx[tid] += t;
        __syncthreads();
    }
    if (tid < BKT_NODES) {
        int ex = hx[tid] - h[tid];
        hx[tid] = ex;
        int n = (bk << BKT_SHIFT) + tid;
        if (n < N) { deg[n] = h[tid]; offs[n] = beg + ex; }
    }
    __syncthreads();
    // scatter to LDS by dst
    for (int s = beg + tid; s < end; s += 256) {
        int d = dib[s];
        int r = atomicAdd(&c[d], 1);
        int op = hx[d] + r;
        float4 v = ebuf[s];
        if (op < CAPB) outbuf[op] = v;
        else payload[beg + op] = v;            // statistically never
    }
    __syncthreads();
    // stream out
    int lim = cnt < CAPB ? cnt : CAPB;
    for (int s = tid; s < lim; s += 256)
        payload[beg + s] = outbuf[s];
}

// ===== K5: one WAVE per node, 8 k-lanes x 8 segments, 4-slot MLP batch =====
__global__ void agg_wave(const float* __restrict__ levels,
                         const float4* __restrict__ node_q,
                         const unsigned long long* __restrict__ qltab,
                         const int* __restrict__ deg,
                         const int* __restrict__ offs,
                         const float4* __restrict__ payload,
                         float4* __restrict__ out_q,
                         float* __restrict__ out_lvl, int N) {
    int t = blockIdx.x * blockDim.x + threadIdx.x;
    int n = t >> 6;                 // one wave64 per node
    if (n >= N) return;
    int lane = t & 63;
    int k = lane & 7;
    int seg = lane >> 3;

    const float QS = 1.0f / 4095.0f;
    float den = 0.f, lv = 0.f, aw = 0.f, ax = 0.f, ay = 0.f, az = 0.f;

    int cnt = deg[n];
    const float4* bp = payload + offs[n];

    for (int j0 = seg; j0 < cnt; j0 += 32) {
        float4 pe[4];
        bool v[4];
#pragma unroll
        for (int s = 0; s < 4; ++s) {           // phase 1: independent loads
            int j = j0 + s * 8;
            v[s] = (j < cnt);
            if (v[s]) pe[s] = bp[j];
        }
        unsigned long long g[4];
#pragma unroll
        for (int s = 0; s < 4; ++s)             // phase 2: independent gathers
            if (v[s])
                g[s] = qltab[(int)__builtin_bit_cast(uint4, pe[s]).w + k];
#pragma unroll
        for (int s = 0; s < 4; ++s)             // phase 3: accumulate
            if (v[s]) {
                uint4 pu = __builtin_bit_cast(uint4, pe[s]);
                float2 r01 = unpack_h2(pu.x);   // (w,x)
                float2 r23 = unpack_h2(pu.y);   // (y,z)
                float tw = __builtin_bit_cast(float, pu.z);
                unsigned long long p = g[s];
                float ls = (float)(unsigned)(p & 0xFFFu) * QS;
                float qw = (float)sext13((unsigned)((p >> 12) & 0x1FFFu)) * QS;
                float qx = (float)sext13((unsigned)((p >> 25) & 0x1FFFu)) * QS;
                float qy = (float)sext13((unsigned)((p >> 38) & 0x1FFFu)) * QS;
                float qz = (float)sext13((unsigned)((p >> 51) & 0x1FFFu)) * QS;
                float ex = __expf(tw * ls - MSHIFT);
                den += ex;
                lv += ex * ls;
                float rw = r01.x, rx = r01.y, ry = r23.x, rz = r23.y;
                aw += ex * (rw * qw - rx * qx - ry * qy - rz * qz);
                ax += ex * (rw * qx + rx * qw + ry * qz - rz * qy);
                ay += ex * (rw * qy - rx * qz + ry * qw + rz * qx);
                az += ex * (rw * qz + rx * qy - ry * qx + rz * qw);
            }
    }

#pragma unroll
    for (int m = 8; m <= 32; m <<= 1) {
        den += __shfl_xor(den, m, 64);
        lv  += __shfl_xor(lv,  m, 64);
        aw  += __shfl_xor(aw,  m, 64);
        ax  += __shfl_xor(ax,  m, 64);
        ay  += __shfl_xor(ay,  m, 64);
        az  += __shfl_xor(az,  m, 64);
    }

    if (seg == 0) {
        int i = n * KDIM + k;
        float l = levels[i];
        float es = __expf(TEMP * l - MSHIFT);
        den += es;
        lv += es * l;
        float4 q0 = node_q[i];
        aw += es * q0.x; ax += es * q0.y; ay += es * q0.z; az += es * q0.w;

        float inv = 1.0f / den;
        lv *= inv; aw *= inv; ax *= inv; ay *= inv; az *= inv;
        float nn = sqrtf(aw * aw + ax * ax + ay * ay + az * az);
        nn = fmaxf(nn, 1e-12f);
        float rn = 1.0f / nn;
        float4 o;
        o.x = aw * rn; o.y = ax * rn; o.z = ay * rn; o.w = az * rn;
        out_q[i] = o;
        out_lvl[i] = lv;
    }
}

// ================= fallback path (round-3 CSR pipeline, f32 payload) =================

__global__ void rank_kernel(const int* __restrict__ edst, int* __restrict__ deg,
                            int* __restrict__ rank, int E) {
    int e = blockIdx.x * blockDim.x + threadIdx.x;
    if (e < E) rank[e] = atomicAdd(&deg[edst[e]], 1);
}

__global__ void scan1(const int* __restrict__ deg, int* __restrict__ offs,
                      int* __restrict__ bsum, int N) {
    __shared__ int s[256];
    int i = blockIdx.x * 256 + threadIdx.x;
    int v = (i < N) ? deg[i] : 0;
    s[threadIdx.x] = v;
    __syncthreads();
    for (int off = 1; off < 256; off <<= 1) {
        int t = (threadIdx.x >= off) ? s[threadIdx.x - off] : 0;
        __syncthreads();
        s[threadIdx.x] += t;
        __syncthreads();
    }
    if (i < N) offs[i] = s[threadIdx.x] - v;
    if (threadIdx.x == 255) bsum[blockIdx.x] = s[255];
}

__global__ void scan2(int* __restrict__ bsum, int nb) {
    __shared__ int s[1024];
    __shared__ int carry_s;
    if (threadIdx.x == 0) carry_s = 0;
    __syncthreads();
    for (int base = 0; base < nb; base += 1024) {
        int idx = base + threadIdx.x;
        int v = (idx < nb) ? bsum[idx] : 0;
        s[threadIdx.x] = v;
        __syncthreads();
        for (int off = 1; off < 1024; off <<= 1) {
            int t = (threadIdx.x >= off) ? s[threadIdx.x - off] : 0;
            __syncthreads();
            s[threadIdx.x] += t;
            __syncthreads();
        }
        if (idx < nb) bsum[idx] = s[threadIdx.x] - v + carry_s;
        __syncthreads();
        if (threadIdx.x == 0) carry_s += s[1023];
        __syncthreads();
    }
}

__global__ void scan3(int* __restrict__ offs, const int* __restrict__ bsum,
                      int N, int E) {
    int i = blockIdx.x * 256 + threadIdx.x;
    if (i < N) offs[i] += bsum[blockIdx.x];
    if (i == 0) offs[N] = E;
}

__global__ void permute_kernel(const int* __restrict__ edst,
                               const int* __restrict__ rank,
                               const int* __restrict__ offs,
                               const float4* __restrict__ rel_q,
                               const float* __restrict__ ew,
                               const int* __restrict__ esrc,
                               float4* __restrict__ payload, int E) {
    int e = blockIdx.x * blockDim.x + threadIdx.x;
    if (e >= E) return;
    int pos = offs[edst[e]] + rank[e];
    payload[2 * pos] = rel_q[e];
    float4 m;
    m.x = TEMP * ew[e];
    m.y = __int_as_float(esrc[e] * KDIM);
    m.z = 0.0f; m.w = 0.0f;
    payload[2 * pos + 1] = m;
}

__global__ void agg_payload(const float* __restrict__ levels,
                            const float4* __restrict__ node_q,
                            const int* __restrict__ offs,
                            const float4* __restrict__ payload,
                            float4* __restrict__ out_q,
                            float* __restrict__ out_lvl, int N) {
    int t = blockIdx.x * blockDim.x + threadIdx.x;
    int n = t >> 3;
    int k = t & 7;
    if (n >= N) return;
    int i = n * KDIM + k;
    float l = levels[i];
    float es = __expf(TEMP * l - MSHIFT);
    float den = es, lv = es * l;
    float4 q0 = node_q[i];
    float aw = es * q0.x, ax = es * q0.y, ay = es * q0.z, az = es * q0.w;
    int beg = offs[n], end = offs[n + 1];
#pragma unroll 2
    for (int j = beg; j < end; j++) {
        float4 r = payload[2 * j];
        float4 m = payload[2 * j + 1];
        float tw = m.x;
        int src8 = __float_as_int(m.y);
        float ls = levels[src8 + k];
        float ex = __expf(tw * ls - MSHIFT);
        float4 q = node_q[src8 + k];
        den += ex;
        lv += ex * ls;
        aw += ex * (r.x * q.x - r.y * q.y - r.z * q.z - r.w * q.w);
        ax += ex * (r.x * q.y + r.y * q.x + r.z * q.w - r.w * q.z);
        ay += ex * (r.x * q.z - r.y * q.w + r.z * q.x + r.w * q.y);
        az += ex * (r.x * q.w + r.y * q.z - r.z * q.y + r.w * q.x);
    }
    float inv = 1.0f / den;
    lv *= inv; aw *= inv; ax *= inv; ay *= inv; az *= inv;
    float nn = sqrtf(aw * aw + ax * ax + ay * ay + az * az);
    nn = fmaxf(nn, 1e-12f);
    float rn = 1.0f / nn;
    float4 o;
    o.x = aw * rn; o.y = ax * rn; o.z = ay * rn; o.w = az * rn;
    out_q[i] = o;
    out_lvl[i] = lv;
}

extern "C" void kernel_launch(void* const* d_in, const int* in_sizes, int n_in,
                              void* d_out, int out_size, void* d_ws, size_t ws_size,
                              hipStream_t stream) {
    const float*  levels = (const float*)d_in[0];   // [N,K]
    const float4* node_q = (const float4*)d_in[1];  // [N,K,4]
    const float4* rel_q  = (const float4*)d_in[2];  // [E,4]
    const float*  ew     = (const float*)d_in[3];   // [E]
    const int*    esrc   = (const int*)d_in[4];     // [E]
    const int*    edst   = (const int*)d_in[5];     // [E]

    const int NK = in_sizes[0];
    const int E  = in_sizes[3];
    const int N  = NK / KDIM;
    const int B  = 256;
    const int gE = (E + B - 1) / B;
    const int gN = (NK + B - 1) / B;

    float* out_q   = (float*)d_out;
    float* out_lvl = (float*)d_out + (size_t)NK * 4;

    // ---- primary layout: ghist|gbase|gcursor|deg|offs|qltab|dib|ebuf|payload ----
    const int NBKT = (N + BKT_NODES - 1) >> BKT_SHIFT;
    const int HB   = (E + EPB_H - 1) / EPB_H;
    auto al = [](size_t x) { return (x + 255) & ~(size_t)255; };
    size_t o_ghist = 0;
    size_t o_gbase = o_ghist + al((size_t)MAXNB * 4);
    size_t o_gcur  = o_gbase + al((size_t)(MAXNB + 1) * 4);
    size_t o_deg   = o_gcur  + al((size_t)MAXNB * 4);
    size_t o_offs  = o_deg   + al((size_t)N * 4);
    size_t o_qltab = o_offs  + al((size_t)N * 4);
    size_t o_dib   = o_qltab + al((size_t)NK * 8);
    size_t o_ebuf  = o_dib   + al((size_t)E);
    size_t o_pay   = o_ebuf  + al((size_t)E * 16);
    size_t need    = o_pay   + al((size_t)E * 16);

    if (NBKT <= MAXNB && ws_size >= need) {
        int* ghist   = (int*)((char*)d_ws + o_ghist);
        int* gbase   = (int*)((char*)d_ws + o_gbase);
        int* gcursor = (int*)((char*)d_ws + o_gcur);
        int* deg     = (int*)((char*)d_ws + o_deg);
        int* offs    = (int*)((char*)d_ws + o_offs);
        unsigned long long* qltab = (unsigned long long*)((char*)d_ws + o_qltab);
        unsigned char* dib = (unsigned char*)((char*)d_ws + o_dib);
        float4* ebuf    = (float4*)((char*)d_ws + o_ebuf);
        float4* payload = (float4*)((char*)d_ws + o_pay);

        (void)hipMemsetAsync(ghist, 0, (size_t)MAXNB * 4, stream);
        prep_hist<<<gN + HB, B, 0, stream>>>(levels, node_q, qltab, NK, gN,
                                             edst, ghist, E);
        scan_buckets<<<1, 1024, 0, stream>>>(ghist, gbase, gcursor, NBKT, E);
        int PB = (E + TILE - 1) / TILE;
        partition_lds<<<PB, PTHR, 0, stream>>>(edst, esrc, ew, rel_q, gcursor,
                                               ebuf, dib, E);
        fine_lds<<<NBKT, B, 0, stream>>>(gbase, ebuf, dib, payload, deg, offs, N);
        int gW = (int)(((size_t)N * 64 + B - 1) / B);   // one wave64 per node
        agg_wave<<<gW, B, 0, stream>>>(levels, node_q, qltab, deg, offs,
                                       payload, (float4*)out_q, out_lvl, N);
        return;
    }

    // ---- fallback: round-3 CSR pipeline ----
    const int nb = (N + 255) / 256;
    int* deg  = (int*)d_ws;
    int* offs = deg + N;
    int* bsum = offs + N + 1;
    size_t prefix = (size_t)(2 * N + 1 + nb);
    int* rank = bsum + nb;
    size_t pay_off = (prefix + E + 3) & ~(size_t)3;
    float4* payload = (float4*)((int*)d_ws + pay_off);

    (void)hipMemsetAsync(deg, 0, (size_t)N * sizeof(int), stream);
    rank_kernel<<<gE, B, 0, stream>>>(edst, deg, rank, E);
    scan1<<<nb, 256, 0, stream>>>(deg, offs, bsum, N);
    scan2<<<1, 1024, 0, stream>>>(bsum, nb);
    scan3<<<nb, 256, 0, stream>>>(offs, bsum, N, E);
    permute_kernel<<<gE, B, 0, stream>>>(edst, rank, offs, rel_q, ew, esrc,
                                         payload, E);
    agg_payload<<<gN, B, 0, stream>>>(levels, node_q, offs, payload,
                                      (float4*)out_q, out_lvl, N);
}

// Round 11
// 316.703 us; speedup vs baseline: 1.0534x; 1.0534x over previous
//
#include <hip/hip_runtime.h>
#include <hip/hip_fp16.h>

#define TEMP 8.0f
#define MSHIFT 8.0f   // constant softmax shift; scores in [0,8) so exp in (e^-8, 1]
#define KDIM 8
#define BKT_SHIFT 6                 // 64 nodes per dst-bucket
#define BKT_NODES (1 << BKT_SHIFT)
#define MAXNB 2048                  // bucket arrays (N <= 131072)
#define TILE 6144                   // edges per partition tile (LDS-sorted)
#define PTHR 512
#define EPT 12                      // TILE / PTHR
#define EPB_H 8192                  // edges per histogram block
#define CAPB 3008                   // fine-pass LDS out-buffer entries (mean 2046, +21sd)
// Evidence ledger (r3-r10):
//  - padding/splits/LLC-fit/NT: no effect. r7 unstaged partition: regressed.
//  - r8: L2-resident table didn't speed gathers -> cost is REQUEST SLOTS, not DRAM.
//  - r9: 4-slot MLP agg -20us (per-wave ILP helps until slot pool saturates).
//  - r10: LDS tile-sort partition: WRITE_SIZE 210->78MB (DRAM merging achieved)
//    but time unchanged -- flush was ONE THREAD PER BUCKET, so each wave-store
//    touched 64 distinct lines AT ISSUE. Slot-requests unchanged. MODEL SHARPENED:
//    ~33G line-requests/s at ISSUE; merging must be within the wave instruction.
//  - THIS ROUND: lane-coalesced flush (sbk[pos] bucket-id, gpos[] cursors,
//    cooperative pos-strided copy -> consecutive lanes hit the same run).
//    Store slot-requests 3.2M -> ~0.9M.

__device__ __forceinline__ unsigned pack_h2(float a, float b) {
    __half2 h = __floats2half2_rn(a, b);
    return __builtin_bit_cast(unsigned, h);
}
__device__ __forceinline__ float2 unpack_h2(unsigned v) {
    __half2 h = __builtin_bit_cast(__half2, v);
    return __half22float2(h);
}

__device__ __forceinline__ unsigned long long pack_ql(float4 q, float l) {
    int lu = __float2int_rn(l * 4095.0f);
    lu = lu < 0 ? 0 : (lu > 4095 ? 4095 : lu);
    int vw = __float2int_rn(q.x * 4095.0f);
    int vx = __float2int_rn(q.y * 4095.0f);
    int vy = __float2int_rn(q.z * 4095.0f);
    int vz = __float2int_rn(q.w * 4095.0f);
    return (unsigned long long)(unsigned)lu
         | ((unsigned long long)((unsigned)vw & 0x1FFFu) << 12)
         | ((unsigned long long)((unsigned)vx & 0x1FFFu) << 25)
         | ((unsigned long long)((unsigned)vy & 0x1FFFu) << 38)
         | ((unsigned long long)((unsigned)vz & 0x1FFFu) << 51);
}

__device__ __forceinline__ int sext13(unsigned v) {
    return ((int)(v << 19)) >> 19;
}

// ===== K1: blocks [0,gN) build qltab; blocks [gN,..) LDS-histogram buckets =====
__global__ void prep_hist(const float* __restrict__ levels,
                          const float4* __restrict__ node_q,
                          unsigned long long* __restrict__ qltab, int NK, int gN,
                          const int* __restrict__ edst,
                          int* __restrict__ ghist, int E) {
    __shared__ int h[MAXNB];
    if ((int)blockIdx.x < gN) {
        int i = blockIdx.x * blockDim.x + threadIdx.x;
        if (i >= NK) return;
        qltab[i] = pack_ql(node_q[i], levels[i]);
    } else {
        int tid = threadIdx.x;
        for (int i = tid; i < MAXNB; i += 256) h[i] = 0;
        __syncthreads();
        int beg = (blockIdx.x - gN) * EPB_H;
        int end = beg + EPB_H; if (end > E) end = E;
        for (int e = beg + tid; e < end; e += 256)
            atomicAdd(&h[edst[e] >> BKT_SHIFT], 1);
        __syncthreads();
        for (int i = tid; i < MAXNB; i += 256)
            if (h[i]) atomicAdd(&ghist[i], h[i]);   // non-returning, L2-hot
    }
}

// ===== K2: exclusive scan of bucket counts (1 block, 1024 thr, 2 chunks) =====
__global__ void scan_buckets(const int* __restrict__ ghist,
                             int* __restrict__ gbase,
                             int* __restrict__ gcursor, int NBKT, int E) {
    __shared__ int s[1024];
    __shared__ int carry_s;
    int tid = threadIdx.x;
    if (tid == 0) carry_s = 0;
    __syncthreads();
    for (int base = 0; base < MAXNB; base += 1024) {
        int idx = base + tid;
        int v = (idx < NBKT) ? ghist[idx] : 0;
        s[tid] = v;
        __syncthreads();
        for (int off = 1; off < 1024; off <<= 1) {
            int t = (tid >= off) ? s[tid - off] : 0;
            __syncthreads();
            s[tid] += t;
            __syncthreads();
        }
        if (idx < NBKT) {
            int b = s[tid] - v + carry_s;
            gbase[idx] = b;
            gcursor[idx] = b;
        }
        __syncthreads();
        if (tid == 0) carry_s += s[1023];
        __syncthreads();
    }
    if (tid == 0) gbase[NBKT] = E;
}

// ===== K3: LDS tile-sort partition with LANE-COALESCED flush =====
__global__ void __launch_bounds__(PTHR, 1)
partition_lds(const int* __restrict__ edst,
              const int* __restrict__ esrc,
              const float* __restrict__ ew,
              const float4* __restrict__ rel_q,
              int* __restrict__ gcursor,
              float4* __restrict__ ebuf,
              unsigned char* __restrict__ dib, int E) {
    __shared__ float4 sortbuf[TILE];          // 96 KB
    __shared__ unsigned char sdib[TILE];      // 6 KB
    __shared__ unsigned short sbk[TILE];      // 12 KB: bucket id per position
    __shared__ int cnt[MAXNB];                // 8 KB
    __shared__ int base[MAXNB];               // 8 KB
    __shared__ int gpos[MAXNB];               // 8 KB: global cursor per bucket
    __shared__ int ts[PTHR];                  // 2 KB     (total ~140 KB)

    int tid = threadIdx.x;
    int tbeg = blockIdx.x * TILE;
    int tcnt = E - tbeg; if (tcnt > TILE) tcnt = TILE;

    for (int i = tid; i < MAXNB; i += PTHR) cnt[i] = 0;
    __syncthreads();

    // phase 1: count, remember (bucket, rank, dib) per edge
    int eb[EPT]; int er[EPT]; unsigned char ed[EPT]; bool ev[EPT];
#pragma unroll
    for (int i = 0; i < EPT; ++i) {
        int e = tbeg + i * PTHR + tid;
        ev[i] = (e < E);
        if (ev[i]) {
            int d = edst[e];
            eb[i] = d >> BKT_SHIFT;
            ed[i] = (unsigned char)(d & (BKT_NODES - 1));
            er[i] = atomicAdd(&cnt[eb[i]], 1);
        }
    }
    __syncthreads();

    // phase 2: exclusive scan of cnt -> base (4 buckets/thread + block scan)
    int loc = 0;
#pragma unroll
    for (int j = 0; j < 4; ++j) {
        int b = tid * 4 + j;
        base[b] = loc;
        loc += cnt[b];
    }
    ts[tid] = loc;
    __syncthreads();
    for (int off = 1; off < PTHR; off <<= 1) {
        int t = (tid >= off) ? ts[tid - off] : 0;
        __syncthreads();
        ts[tid] += t;
        __syncthreads();
    }
    int tb = ts[tid] - loc;   // exclusive thread base
#pragma unroll
    for (int j = 0; j < 4; ++j) base[tid * 4 + j] += tb;
    __syncthreads();

    // phase 3: build records, scatter into LDS (bucket-sorted)
#pragma unroll
    for (int i = 0; i < EPT; ++i) {
        if (ev[i]) {
            int e = tbeg + i * PTHR + tid;
            float4 rq = rel_q[e];
            uint4 u;
            u.x = pack_h2(rq.x, rq.y);
            u.y = pack_h2(rq.z, rq.w);
            u.z = __builtin_bit_cast(unsigned, TEMP * ew[e]);
            u.w = (unsigned)(esrc[e] * KDIM);
            int pos = base[eb[i]] + er[i];
            sortbuf[pos] = __builtin_bit_cast(float4, u);
            sdib[pos] = ed[i];
            sbk[pos] = (unsigned short)eb[i];
        }
    }
    __syncthreads();

    // phase 4a: one cursor atomic per bucket -> gpos
    for (int b = tid; b < MAXNB; b += PTHR)
        if (cnt[b]) gpos[b] = atomicAdd(&gcursor[b], cnt[b]);
    __syncthreads();

    // phase 4b: LANE-COALESCED flush: consecutive lanes write consecutive
    // positions of the same bucket run -> 16B x 4 lanes merge per line AT ISSUE.
    for (int pos = tid; pos < tcnt; pos += PTHR) {
        int b = sbk[pos];
        int dst = gpos[b] + (pos - base[b]);
        ebuf[dst] = sortbuf[pos];
        dib[dst] = sdib[pos];
    }
}

// ===== K4: fine scatter inside LDS, one block per bucket; stream out dense
// CSR payload + exact deg/offs =====
__global__ void fine_lds(const int* __restrict__ gbase,
                         const float4* __restrict__ ebuf,
                         const unsigned char* __restrict__ dib,
                         float4* __restrict__ payload,
                         int* __restrict__ deg,
                         int* __restrict__ offs, int N) {
    __shared__ float4 outbuf[CAPB];           // 48 KB
    __shared__ int h[BKT_NODES];
    __shared__ int hx[BKT_NODES];
    __shared__ int c[BKT_NODES];
    int bk = blockIdx.x;
    int tid = threadIdx.x;
    int beg = gbase[bk], end = gbase[bk + 1];
    int cnt = end - beg;

    if (tid < BKT_NODES) { h[tid] = 0; c[tid] = 0; }
    __syncthreads();
    for (int s = beg + tid; s < end; s += 256)
        atomicAdd(&h[dib[s]], 1);
    __syncthreads();
    if (tid < BKT_NODES) hx[tid] = h[tid];
    __syncthreads();
    for (int off = 1; off < BKT_NODES; off <<= 1) {
        int t = (tid >= off && tid < BKT_NODES) ? hx[tid - off] : 0;
        __syncthreads();
        if (tid < BKT_NODES) hx[tid] += t;
        __syncthreads();
    }
    if (tid < BKT_NODES) {
        int ex = hx[tid] - h[tid];
        hx[tid] = ex;
        int n = (bk << BKT_SHIFT) + tid;
        if (n < N) { deg[n] = h[tid]; offs[n] = beg + ex; }
    }
    __syncthreads();
    for (int s = beg + tid; s < end; s += 256) {
        int d = dib[s];
        int r = atomicAdd(&c[d], 1);
        int op = hx[d] + r;
        float4 v = ebuf[s];
        if (op < CAPB) outbuf[op] = v;
        else payload[beg + op] = v;            // statistically never
    }
    __syncthreads();
    int lim = cnt < CAPB ? cnt : CAPB;
    for (int s = tid; s < lim; s += 256)
        payload[beg + s] = outbuf[s];
}

// ===== K5: one WAVE per node, 8 k-lanes x 8 segments, 4-slot MLP batch =====
__global__ void agg_wave(const float* __restrict__ levels,
                         const float4* __restrict__ node_q,
                         const unsigned long long* __restrict__ qltab,
                         const int* __restrict__ deg,
                         const int* __restrict__ offs,
                         const float4* __restrict__ payload,
                         float4* __restrict__ out_q,
                         float* __restrict__ out_lvl, int N) {
    int t = blockIdx.x * blockDim.x + threadIdx.x;
    int n = t >> 6;                 // one wave64 per node
    if (n >= N) return;
    int lane = t & 63;
    int k = lane & 7;
    int seg = lane >> 3;

    const float QS = 1.0f / 4095.0f;
    float den = 0.f, lv = 0.f, aw = 0.f, ax = 0.f, ay = 0.f, az = 0.f;

    int cnt = deg[n];
    const float4* bp = payload + offs[n];

    for (int j0 = seg; j0 < cnt; j0 += 32) {
        float4 pe[4];
        bool v[4];
#pragma unroll
        for (int s = 0; s < 4; ++s) {           // phase 1: independent loads
            int j = j0 + s * 8;
            v[s] = (j < cnt);
            if (v[s]) pe[s] = bp[j];
        }
        unsigned long long g[4];
#pragma unroll
        for (int s = 0; s < 4; ++s)             // phase 2: independent gathers
            if (v[s])
                g[s] = qltab[(int)__builtin_bit_cast(uint4, pe[s]).w + k];
#pragma unroll
        for (int s = 0; s < 4; ++s)             // phase 3: accumulate
            if (v[s]) {
                uint4 pu = __builtin_bit_cast(uint4, pe[s]);
                float2 r01 = unpack_h2(pu.x);   // (w,x)
                float2 r23 = unpack_h2(pu.y);   // (y,z)
                float tw = __builtin_bit_cast(float, pu.z);
                unsigned long long p = g[s];
                float ls = (float)(unsigned)(p & 0xFFFu) * QS;
                float qw = (float)sext13((unsigned)((p >> 12) & 0x1FFFu)) * QS;
                float qx = (float)sext13((unsigned)((p >> 25) & 0x1FFFu)) * QS;
                float qy = (float)sext13((unsigned)((p >> 38) & 0x1FFFu)) * QS;
                float qz = (float)sext13((unsigned)((p >> 51) & 0x1FFFu)) * QS;
                float ex = __expf(tw * ls - MSHIFT);
                den += ex;
                lv += ex * ls;
                float rw = r01.x, rx = r01.y, ry = r23.x, rz = r23.y;
                aw += ex * (rw * qw - rx * qx - ry * qy - rz * qz);
                ax += ex * (rw * qx + rx * qw + ry * qz - rz * qy);
                ay += ex * (rw * qy - rx * qz + ry * qw + rz * qx);
                az += ex * (rw * qz + rx * qy - ry * qx + rz * qw);
            }
    }

#pragma unroll
    for (int m = 8; m <= 32; m <<= 1) {
        den += __shfl_xor(den, m, 64);
        lv  += __shfl_xor(lv,  m, 64);
        aw  += __shfl_xor(aw,  m, 64);
        ax  += __shfl_xor(ax,  m, 64);
        ay  += __shfl_xor(ay,  m, 64);
        az  += __shfl_xor(az,  m, 64);
    }

    if (seg == 0) {
        int i = n * KDIM + k;
        float l = levels[i];
        float es = __expf(TEMP * l - MSHIFT);
        den += es;
        lv += es * l;
        float4 q0 = node_q[i];
        aw += es * q0.x; ax += es * q0.y; ay += es * q0.z; az += es * q0.w;

        float inv = 1.0f / den;
        lv *= inv; aw *= inv; ax *= inv; ay *= inv; az *= inv;
        float nn = sqrtf(aw * aw + ax * ax + ay * ay + az * az);
        nn = fmaxf(nn, 1e-12f);
        float rn = 1.0f / nn;
        float4 o;
        o.x = aw * rn; o.y = ax * rn; o.z = ay * rn; o.w = az * rn;
        out_q[i] = o;
        out_lvl[i] = lv;
    }
}

// ================= fallback path (round-3 CSR pipeline, f32 payload) =================

__global__ void rank_kernel(const int* __restrict__ edst, int* __restrict__ deg,
                            int* __restrict__ rank, int E) {
    int e = blockIdx.x * blockDim.x + threadIdx.x;
    if (e < E) rank[e] = atomicAdd(&deg[edst[e]], 1);
}

__global__ void scan1(const int* __restrict__ deg, int* __restrict__ offs,
                      int* __restrict__ bsum, int N) {
    __shared__ int s[256];
    int i = blockIdx.x * 256 + threadIdx.x;
    int v = (i < N) ? deg[i] : 0;
    s[threadIdx.x] = v;
    __syncthreads();
    for (int off = 1; off < 256; off <<= 1) {
        int t = (threadIdx.x >= off) ? s[threadIdx.x - off] : 0;
        __syncthreads();
        s[threadIdx.x] += t;
        __syncthreads();
    }
    if (i < N) offs[i] = s[threadIdx.x] - v;
    if (threadIdx.x == 255) bsum[blockIdx.x] = s[255];
}

__global__ void scan2(int* __restrict__ bsum, int nb) {
    __shared__ int s[1024];
    __shared__ int carry_s;
    if (threadIdx.x == 0) carry_s = 0;
    __syncthreads();
    for (int base = 0; base < nb; base += 1024) {
        int idx = base + threadIdx.x;
        int v = (idx < nb) ? bsum[idx] : 0;
        s[threadIdx.x] = v;
        __syncthreads();
        for (int off = 1; off < 1024; off <<= 1) {
            int t = (threadIdx.x >= off) ? s[threadIdx.x - off] : 0;
            __syncthreads();
            s[threadIdx.x] += t;
            __syncthreads();
        }
        if (idx < nb) bsum[idx] = s[threadIdx.x] - v + carry_s;
        __syncthreads();
        if (threadIdx.x == 0) carry_s += s[1023];
        __syncthreads();
    }
}

__global__ void scan3(int* __restrict__ offs, const int* __restrict__ bsum,
                      int N, int E) {
    int i = blockIdx.x * 256 + threadIdx.x;
    if (i < N) offs[i] += bsum[blockIdx.x];
    if (i == 0) offs[N] = E;
}

__global__ void permute_kernel(const int* __restrict__ edst,
                               const int* __restrict__ rank,
                               const int* __restrict__ offs,
                               const float4* __restrict__ rel_q,
                               const float* __restrict__ ew,
                               const int* __restrict__ esrc,
                               float4* __restrict__ payload, int E) {
    int e = blockIdx.x * blockDim.x + threadIdx.x;
    if (e >= E) return;
    int pos = offs[edst[e]] + rank[e];
    payload[2 * pos] = rel_q[e];
    float4 m;
    m.x = TEMP * ew[e];
    m.y = __int_as_float(esrc[e] * KDIM);
    m.z = 0.0f; m.w = 0.0f;
    payload[2 * pos + 1] = m;
}

__global__ void agg_payload(const float* __restrict__ levels,
                            const float4* __restrict__ node_q,
                            const int* __restrict__ offs,
                            const float4* __restrict__ payload,
                            float4* __restrict__ out_q,
                            float* __restrict__ out_lvl, int N) {
    int t = blockIdx.x * blockDim.x + threadIdx.x;
    int n = t >> 3;
    int k = t & 7;
    if (n >= N) return;
    int i = n * KDIM + k;
    float l = levels[i];
    float es = __expf(TEMP * l - MSHIFT);
    float den = es, lv = es * l;
    float4 q0 = node_q[i];
    float aw = es * q0.x, ax = es * q0.y, ay = es * q0.z, az = es * q0.w;
    int beg = offs[n], end = offs[n + 1];
#pragma unroll 2
    for (int j = beg; j < end; j++) {
        float4 r = payload[2 * j];
        float4 m = payload[2 * j + 1];
        float tw = m.x;
        int src8 = __float_as_int(m.y);
        float ls = levels[src8 + k];
        float ex = __expf(tw * ls - MSHIFT);
        float4 q = node_q[src8 + k];
        den += ex;
        lv += ex * ls;
        aw += ex * (r.x * q.x - r.y * q.y - r.z * q.z - r.w * q.w);
        ax += ex * (r.x * q.y + r.y * q.x + r.z * q.w - r.w * q.z);
        ay += ex * (r.x * q.z - r.y * q.w + r.z * q.x + r.w * q.y);
        az += ex * (r.x * q.w + r.y * q.z - r.z * q.y + r.w * q.x);
    }
    float inv = 1.0f / den;
    lv *= inv; aw *= inv; ax *= inv; ay *= inv; az *= inv;
    float nn = sqrtf(aw * aw + ax * ax + ay * ay + az * az);
    nn = fmaxf(nn, 1e-12f);
    float rn = 1.0f / nn;
    float4 o;
    o.x = aw * rn; o.y = ax * rn; o.z = ay * rn; o.w = az * rn;
    out_q[i] = o;
    out_lvl[i] = lv;
}

extern "C" void kernel_launch(void* const* d_in, const int* in_sizes, int n_in,
                              void* d_out, int out_size, void* d_ws, size_t ws_size,
                              hipStream_t stream) {
    const float*  levels = (const float*)d_in[0];   // [N,K]
    const float4* node_q = (const float4*)d_in[1];  // [N,K,4]
    const float4* rel_q  = (const float4*)d_in[2];  // [E,4]
    const float*  ew     = (const float*)d_in[3];   // [E]
    const int*    esrc   = (const int*)d_in[4];     // [E]
    const int*    edst   = (const int*)d_in[5];     // [E]

    const int NK = in_sizes[0];
    const int E  = in_sizes[3];
    const int N  = NK / KDIM;
    const int B  = 256;
    const int gE = (E + B - 1) / B;
    const int gN = (NK + B - 1) / B;

    float* out_q   = (float*)d_out;
    float* out_lvl = (float*)d_out + (size_t)NK * 4;

    // ---- primary layout: ghist|gbase|gcursor|deg|offs|qltab|dib|ebuf|payload ----
    const int NBKT = (N + BKT_NODES - 1) >> BKT_SHIFT;
    const int HB   = (E + EPB_H - 1) / EPB_H;
    auto al = [](size_t x) { return (x + 255) & ~(size_t)255; };
    size_t o_ghist = 0;
    size_t o_gbase = o_ghist + al((size_t)MAXNB * 4);
    size_t o_gcur  = o_gbase + al((size_t)(MAXNB + 1) * 4);
    size_t o_deg   = o_gcur  + al((size_t)MAXNB * 4);
    size_t o_offs  = o_deg   + al((size_t)N * 4);
    size_t o_qltab = o_offs  + al((size_t)N * 4);
    size_t o_dib   = o_qltab + al((size_t)NK * 8);
    size_t o_ebuf  = o_dib   + al((size_t)E);
    size_t o_pay   = o_ebuf  + al((size_t)E * 16);
    size_t need    = o_pay   + al((size_t)E * 16);

    if (NBKT <= MAXNB && ws_size >= need) {
        int* ghist   = (int*)((char*)d_ws + o_ghist);
        int* gbase   = (int*)((char*)d_ws + o_gbase);
        int* gcursor = (int*)((char*)d_ws + o_gcur);
        int* deg     = (int*)((char*)d_ws + o_deg);
        int* offs    = (int*)((char*)d_ws + o_offs);
        unsigned long long* qltab = (unsigned long long*)((char*)d_ws + o_qltab);
        unsigned char* dib = (unsigned char*)((char*)d_ws + o_dib);
        float4* ebuf    = (float4*)((char*)d_ws + o_ebuf);
        float4* payload = (float4*)((char*)d_ws + o_pay);

        (void)hipMemsetAsync(ghist, 0, (size_t)MAXNB * 4, stream);
        prep_hist<<<gN + HB, B, 0, stream>>>(levels, node_q, qltab, NK, gN,
                                             edst, ghist, E);
        scan_buckets<<<1, 1024, 0, stream>>>(ghist, gbase, gcursor, NBKT, E);
        int PB = (E + TILE - 1) / TILE;
        partition_lds<<<PB, PTHR, 0, stream>>>(edst, esrc, ew, rel_q, gcursor,
                                               ebuf, dib, E);
        fine_lds<<<NBKT, B, 0, stream>>>(gbase, ebuf, dib, payload, deg, offs, N);
        int gW = (int)(((size_t)N * 64 + B - 1) / B);   // one wave64 per node
        agg_wave<<<gW, B, 0, stream>>>(levels, node_q, qltab, deg, offs,
                                       payload, (float4*)out_q, out_lvl, N);
        return;
    }

    // ---- fallback: round-3 CSR pipeline ----
    const int nb = (N + 255) / 256;
    int* deg  = (int*)d_ws;
    int* offs = deg + N;
    int* bsum = offs + N + 1;
    size_t prefix = (size_t)(2 * N + 1 + nb);
    int* rank = bsum + nb;
    size_t pay_off = (prefix + E + 3) & ~(size_t)3;
    float4* payload = (float4*)((int*)d_ws + pay_off);

    (void)hipMemsetAsync(deg, 0, (size_t)N * sizeof(int), stream);
    rank_kernel<<<gE, B, 0, stream>>>(edst, deg, rank, E);
    scan1<<<nb, 256, 0, stream>>>(deg, offs, bsum, N);
    scan2<<<1, 1024, 0, stream>>>(bsum, nb);
    scan3<<<nb, 256, 0, stream>>>(offs, bsum, N, E);
    permute_kernel<<<gE, B, 0, stream>>>(edst, rank, offs, rel_q, ew, esrc,
                                         payload, E);
    agg_payload<<<gN, B, 0, stream>>>(levels, node_q, offs, payload,
                                      (float4*)out_q, out_lvl, N);
}

// Round 12
// 310.169 us; speedup vs baseline: 1.0756x; 1.0211x over previous
//
#include <hip/hip_runtime.h>
#include <hip/hip_fp16.h>

#define TEMP 8.0f
#define MSHIFT 8.0f   // constant softmax shift; scores in [0,8) so exp in (e^-8, 1]
#define KDIM 8
#define BKT_SHIFT 7                 // 128 nodes per dst-bucket
#define BKT_NODES (1 << BKT_SHIFT)
#define MAXNB 1024                  // bucket arrays (N <= 131072)
#define TILE 3072                   // edges per partition tile (LDS-sorted)
#define PTHR 512
#define EPT 6                       // TILE / PTHR
#define BPT 2                       // MAXNB / PTHR buckets per thread in scan
#define EPB_H 8192                  // edges per histogram block
#define CAPB 4736                   // fine-pass LDS out-buffer (lambda=4092, +10sd)
// Evidence ledger (r3-r11):
//  - r10/r11: LDS tile-sort + lane-coalesced flush: WRITE 210->78MB AND
//    partition 106->92us. Model: ~33G line-requests/s AT ISSUE; merging must
//    be within the wave instruction. r11 counters: partition Occ=15% (140KB
//    LDS -> 1 blk/CU) + 1.6M LDS bank conflicts -> latency not hidden.
//  - agg ~145us vs ~97us gather floor (3.2M lines): outstanding-request
//    shortfall (24 waves x 4 slots = 96 < ~116 needed).
//  - THIS ROUND: (1) partition LDS 140->71KB (BKT 128 nodes, TILE 3072) ->
//    2 blk/CU; (2) agg MLP 4->6 slots; (3) fine adapted to 128-node buckets.
//  - r8: L2-resident table no help -> request slots, not DRAM. r9 MLP -20us.
//  - NT/padding/splits/LLC-fit: all null. r7 unstaged partition: regressed.

__device__ __forceinline__ unsigned pack_h2(float a, float b) {
    __half2 h = __floats2half2_rn(a, b);
    return __builtin_bit_cast(unsigned, h);
}
__device__ __forceinline__ float2 unpack_h2(unsigned v) {
    __half2 h = __builtin_bit_cast(__half2, v);
    return __half22float2(h);
}

__device__ __forceinline__ unsigned long long pack_ql(float4 q, float l) {
    int lu = __float2int_rn(l * 4095.0f);
    lu = lu < 0 ? 0 : (lu > 4095 ? 4095 : lu);
    int vw = __float2int_rn(q.x * 4095.0f);
    int vx = __float2int_rn(q.y * 4095.0f);
    int vy = __float2int_rn(q.z * 4095.0f);
    int vz = __float2int_rn(q.w * 4095.0f);
    return (unsigned long long)(unsigned)lu
         | ((unsigned long long)((unsigned)vw & 0x1FFFu) << 12)
         | ((unsigned long long)((unsigned)vx & 0x1FFFu) << 25)
         | ((unsigned long long)((unsigned)vy & 0x1FFFu) << 38)
         | ((unsigned long long)((unsigned)vz & 0x1FFFu) << 51);
}

__device__ __forceinline__ int sext13(unsigned v) {
    return ((int)(v << 19)) >> 19;
}

// ===== K1: blocks [0,gN) build qltab; blocks [gN,..) LDS-histogram buckets =====
__global__ void prep_hist(const float* __restrict__ levels,
                          const float4* __restrict__ node_q,
                          unsigned long long* __restrict__ qltab, int NK, int gN,
                          const int* __restrict__ edst,
                          int* __restrict__ ghist, int E) {
    __shared__ int h[MAXNB];
    if ((int)blockIdx.x < gN) {
        int i = blockIdx.x * blockDim.x + threadIdx.x;
        if (i >= NK) return;
        qltab[i] = pack_ql(node_q[i], levels[i]);
    } else {
        int tid = threadIdx.x;
        for (int i = tid; i < MAXNB; i += 256) h[i] = 0;
        __syncthreads();
        int beg = (blockIdx.x - gN) * EPB_H;
        int end = beg + EPB_H; if (end > E) end = E;
        for (int e = beg + tid; e < end; e += 256)
            atomicAdd(&h[edst[e] >> BKT_SHIFT], 1);
        __syncthreads();
        for (int i = tid; i < MAXNB; i += 256)
            if (h[i]) atomicAdd(&ghist[i], h[i]);   // non-returning, L2-hot
    }
}

// ===== K2: exclusive scan of bucket counts (1 block, 1024 thr) =====
__global__ void scan_buckets(const int* __restrict__ ghist,
                             int* __restrict__ gbase,
                             int* __restrict__ gcursor, int NBKT, int E) {
    __shared__ int s[1024];
    __shared__ int carry_s;
    int tid = threadIdx.x;
    if (tid == 0) carry_s = 0;
    __syncthreads();
    for (int base = 0; base < MAXNB; base += 1024) {
        int idx = base + tid;
        int v = (idx < NBKT) ? ghist[idx] : 0;
        s[tid] = v;
        __syncthreads();
        for (int off = 1; off < 1024; off <<= 1) {
            int t = (tid >= off) ? s[tid - off] : 0;
            __syncthreads();
            s[tid] += t;
            __syncthreads();
        }
        if (idx < NBKT) {
            int b = s[tid] - v + carry_s;
            gbase[idx] = b;
            gcursor[idx] = b;
        }
        __syncthreads();
        if (tid == 0) carry_s += s[1023];
        __syncthreads();
    }
    if (tid == 0) gbase[NBKT] = E;
}

// ===== K3: LDS tile-sort partition, lane-coalesced flush, 71KB LDS (2 blk/CU) =====
__global__ void __launch_bounds__(PTHR, 4)
partition_lds(const int* __restrict__ edst,
              const int* __restrict__ esrc,
              const float* __restrict__ ew,
              const float4* __restrict__ rel_q,
              int* __restrict__ gcursor,
              float4* __restrict__ ebuf,
              unsigned char* __restrict__ dib, int E) {
    __shared__ float4 sortbuf[TILE];          // 48 KB
    __shared__ unsigned char sdib[TILE];      // 3 KB
    __shared__ unsigned short sbk[TILE];      // 6 KB: bucket id per position
    __shared__ int cnt[MAXNB];                // 4 KB
    __shared__ int base[MAXNB];               // 4 KB
    __shared__ int gpos[MAXNB];               // 4 KB: global cursor per bucket
    __shared__ int ts[PTHR];                  // 2 KB     (total ~71 KB)

    int tid = threadIdx.x;
    int tbeg = blockIdx.x * TILE;
    int tcnt = E - tbeg; if (tcnt > TILE) tcnt = TILE;

    for (int i = tid; i < MAXNB; i += PTHR) cnt[i] = 0;
    __syncthreads();

    // phase 1: count, remember (bucket, rank, dib) per edge
    int eb[EPT]; int er[EPT]; unsigned char ed[EPT]; bool ev[EPT];
#pragma unroll
    for (int i = 0; i < EPT; ++i) {
        int e = tbeg + i * PTHR + tid;
        ev[i] = (e < E);
        if (ev[i]) {
            int d = edst[e];
            eb[i] = d >> BKT_SHIFT;
            ed[i] = (unsigned char)(d & (BKT_NODES - 1));
            er[i] = atomicAdd(&cnt[eb[i]], 1);
        }
    }
    __syncthreads();

    // phase 2: exclusive scan of cnt -> base (BPT buckets/thread + block scan)
    int loc = 0;
#pragma unroll
    for (int j = 0; j < BPT; ++j) {
        int b = tid * BPT + j;
        base[b] = loc;
        loc += cnt[b];
    }
    ts[tid] = loc;
    __syncthreads();
    for (int off = 1; off < PTHR; off <<= 1) {
        int t = (tid >= off) ? ts[tid - off] : 0;
        __syncthreads();
        ts[tid] += t;
        __syncthreads();
    }
    int tb = ts[tid] - loc;   // exclusive thread base
#pragma unroll
    for (int j = 0; j < BPT; ++j) base[tid * BPT + j] += tb;
    __syncthreads();

    // phase 3: build records, scatter into LDS (bucket-sorted)
#pragma unroll
    for (int i = 0; i < EPT; ++i) {
        if (ev[i]) {
            int e = tbeg + i * PTHR + tid;
            float4 rq = rel_q[e];
            uint4 u;
            u.x = pack_h2(rq.x, rq.y);
            u.y = pack_h2(rq.z, rq.w);
            u.z = __builtin_bit_cast(unsigned, TEMP * ew[e]);
            u.w = (unsigned)(esrc[e] * KDIM);
            int pos = base[eb[i]] + er[i];
            sortbuf[pos] = __builtin_bit_cast(float4, u);
            sdib[pos] = ed[i];
            sbk[pos] = (unsigned short)eb[i];
        }
    }
    __syncthreads();

    // phase 4a: one cursor atomic per bucket -> gpos
    for (int b = tid; b < MAXNB; b += PTHR)
        if (cnt[b]) gpos[b] = atomicAdd(&gcursor[b], cnt[b]);
    __syncthreads();

    // phase 4b: LANE-COALESCED flush: consecutive lanes write consecutive
    // positions of the same bucket run -> merged lines AT ISSUE.
    for (int pos = tid; pos < tcnt; pos += PTHR) {
        int b = sbk[pos];
        int dst = gpos[b] + (pos - base[b]);
        ebuf[dst] = sortbuf[pos];
        dib[dst] = sdib[pos];
    }
}

// ===== K4: fine scatter inside LDS, one block per 128-node bucket =====
__global__ void fine_lds(const int* __restrict__ gbase,
                         const float4* __restrict__ ebuf,
                         const unsigned char* __restrict__ dib,
                         float4* __restrict__ payload,
                         int* __restrict__ deg,
                         int* __restrict__ offs, int N) {
    __shared__ float4 outbuf[CAPB];           // 74 KB
    __shared__ int h[BKT_NODES];
    __shared__ int hx[BKT_NODES];
    __shared__ int c[BKT_NODES];
    int bk = blockIdx.x;
    int tid = threadIdx.x;
    int beg = gbase[bk], end = gbase[bk + 1];
    int cnt = end - beg;

    if (tid < BKT_NODES) { h[tid] = 0; c[tid] = 0; }
    __syncthreads();
    for (int s = beg + tid; s < end; s += 256)
        atomicAdd(&h[dib[s]], 1);
    __syncthreads();
    if (tid < BKT_NODES) hx[tid] = h[tid];
    __syncthreads();
    for (int off = 1; off < BKT_NODES; off <<= 1) {
        int t = (tid >= off && tid < BKT_NODES) ? hx[tid - off] : 0;
        __syncthreads();
        if (tid < BKT_NODES) hx[tid] += t;
        __syncthreads();
    }
    if (tid < BKT_NODES) {
        int ex = hx[tid] - h[tid];
        hx[tid] = ex;
        int n = (bk << BKT_SHIFT) + tid;
        if (n < N) { deg[n] = h[tid]; offs[n] = beg + ex; }
    }
    __syncthreads();
    for (int s = beg + tid; s < end; s += 256) {
        int d = dib[s];
        int r = atomicAdd(&c[d], 1);
        int op = hx[d] + r;
        float4 v = ebuf[s];
        if (op < CAPB) outbuf[op] = v;
        else payload[beg + op] = v;            // statistically never
    }
    __syncthreads();
    int lim = cnt < CAPB ? cnt : CAPB;
    for (int s = tid; s < lim; s += 256)
        payload[beg + s] = outbuf[s];
}

// ===== K5: one WAVE per node, 8 k-lanes x 8 segments, 6-slot MLP batch =====
__global__ void agg_wave(const float* __restrict__ levels,
                         const float4* __restrict__ node_q,
                         const unsigned long long* __restrict__ qltab,
                         const int* __restrict__ deg,
                         const int* __restrict__ offs,
                         const float4* __restrict__ payload,
                         float4* __restrict__ out_q,
                         float* __restrict__ out_lvl, int N) {
    int t = blockIdx.x * blockDim.x + threadIdx.x;
    int n = t >> 6;                 // one wave64 per node
    if (n >= N) return;
    int lane = t & 63;
    int k = lane & 7;
    int seg = lane >> 3;

    const float QS = 1.0f / 4095.0f;
    float den = 0.f, lv = 0.f, aw = 0.f, ax = 0.f, ay = 0.f, az = 0.f;

    int cnt = deg[n];
    const float4* bp = payload + offs[n];

    for (int j0 = seg; j0 < cnt; j0 += 48) {
        float4 pe[6];
        bool v[6];
#pragma unroll
        for (int s = 0; s < 6; ++s) {           // phase 1: independent loads
            int j = j0 + s * 8;
            v[s] = (j < cnt);
            if (v[s]) pe[s] = bp[j];
        }
        unsigned long long g[6];
#pragma unroll
        for (int s = 0; s < 6; ++s)             // phase 2: independent gathers
            if (v[s])
                g[s] = qltab[(int)__builtin_bit_cast(uint4, pe[s]).w + k];
#pragma unroll
        for (int s = 0; s < 6; ++s)             // phase 3: accumulate
            if (v[s]) {
                uint4 pu = __builtin_bit_cast(uint4, pe[s]);
                float2 r01 = unpack_h2(pu.x);   // (w,x)
                float2 r23 = unpack_h2(pu.y);   // (y,z)
                float tw = __builtin_bit_cast(float, pu.z);
                unsigned long long p = g[s];
                float ls = (float)(unsigned)(p & 0xFFFu) * QS;
                float qw = (float)sext13((unsigned)((p >> 12) & 0x1FFFu)) * QS;
                float qx = (float)sext13((unsigned)((p >> 25) & 0x1FFFu)) * QS;
                float qy = (float)sext13((unsigned)((p >> 38) & 0x1FFFu)) * QS;
                float qz = (float)sext13((unsigned)((p >> 51) & 0x1FFFu)) * QS;
                float ex = __expf(tw * ls - MSHIFT);
                den += ex;
                lv += ex * ls;
                float rw = r01.x, rx = r01.y, ry = r23.x, rz = r23.y;
                aw += ex * (rw * qw - rx * qx - ry * qy - rz * qz);
                ax += ex * (rw * qx + rx * qw + ry * qz - rz * qy);
                ay += ex * (rw * qy - rx * qz + ry * qw + rz * qx);
                az += ex * (rw * qz + rx * qy - ry * qx + rz * qw);
            }
    }

#pragma unroll
    for (int m = 8; m <= 32; m <<= 1) {
        den += __shfl_xor(den, m, 64);
        lv  += __shfl_xor(lv,  m, 64);
        aw  += __shfl_xor(aw,  m, 64);
        ax  += __shfl_xor(ax,  m, 64);
        ay  += __shfl_xor(ay,  m, 64);
        az  += __shfl_xor(az,  m, 64);
    }

    if (seg == 0) {
        int i = n * KDIM + k;
        float l = levels[i];
        float es = __expf(TEMP * l - MSHIFT);
        den += es;
        lv += es * l;
        float4 q0 = node_q[i];
        aw += es * q0.x; ax += es * q0.y; ay += es * q0.z; az += es * q0.w;

        float inv = 1.0f / den;
        lv *= inv; aw *= inv; ax *= inv; ay *= inv; az *= inv;
        float nn = sqrtf(aw * aw + ax * ax + ay * ay + az * az);
        nn = fmaxf(nn, 1e-12f);
        float rn = 1.0f / nn;
        float4 o;
        o.x = aw * rn; o.y = ax * rn; o.z = ay * rn; o.w = az * rn;
        out_q[i] = o;
        out_lvl[i] = lv;
    }
}

// ================= fallback path (round-3 CSR pipeline, f32 payload) =================

__global__ void rank_kernel(const int* __restrict__ edst, int* __restrict__ deg,
                            int* __restrict__ rank, int E) {
    int e = blockIdx.x * blockDim.x + threadIdx.x;
    if (e < E) rank[e] = atomicAdd(&deg[edst[e]], 1);
}

__global__ void scan1(const int* __restrict__ deg, int* __restrict__ offs,
                      int* __restrict__ bsum, int N) {
    __shared__ int s[256];
    int i = blockIdx.x * 256 + threadIdx.x;
    int v = (i < N) ? deg[i] : 0;
    s[threadIdx.x] = v;
    __syncthreads();
    for (int off = 1; off < 256; off <<= 1) {
        int t = (threadIdx.x >= off) ? s[threadIdx.x - off] : 0;
        __syncthreads();
        s[threadIdx.x] += t;
        __syncthreads();
    }
    if (i < N) offs[i] = s[threadIdx.x] - v;
    if (threadIdx.x == 255) bsum[blockIdx.x] = s[255];
}

__global__ void scan2(int* __restrict__ bsum, int nb) {
    __shared__ int s[1024];
    __shared__ int carry_s;
    if (threadIdx.x == 0) carry_s = 0;
    __syncthreads();
    for (int base = 0; base < nb; base += 1024) {
        int idx = base + threadIdx.x;
        int v = (idx < nb) ? bsum[idx] : 0;
        s[threadIdx.x] = v;
        __syncthreads();
        for (int off = 1; off < 1024; off <<= 1) {
            int t = (threadIdx.x >= off) ? s[threadIdx.x - off] : 0;
            __syncthreads();
            s[threadIdx.x] += t;
            __syncthreads();
        }
        if (idx < nb) bsum[idx] = s[threadIdx.x] - v + carry_s;
        __syncthreads();
        if (threadIdx.x == 0) carry_s += s[1023];
        __syncthreads();
    }
}

__global__ void scan3(int* __restrict__ offs, const int* __restrict__ bsum,
                      int N, int E) {
    int i = blockIdx.x * 256 + threadIdx.x;
    if (i < N) offs[i] += bsum[blockIdx.x];
    if (i == 0) offs[N] = E;
}

__global__ void permute_kernel(const int* __restrict__ edst,
                               const int* __restrict__ rank,
                               const int* __restrict__ offs,
                               const float4* __restrict__ rel_q,
                               const float* __restrict__ ew,
                               const int* __restrict__ esrc,
                               float4* __restrict__ payload, int E) {
    int e = blockIdx.x * blockDim.x + threadIdx.x;
    if (e >= E) return;
    int pos = offs[edst[e]] + rank[e];
    payload[2 * pos] = rel_q[e];
    float4 m;
    m.x = TEMP * ew[e];
    m.y = __int_as_float(esrc[e] * KDIM);
    m.z = 0.0f; m.w = 0.0f;
    payload[2 * pos + 1] = m;
}

__global__ void agg_payload(const float* __restrict__ levels,
                            const float4* __restrict__ node_q,
                            const int* __restrict__ offs,
                            const float4* __restrict__ payload,
                            float4* __restrict__ out_q,
                            float* __restrict__ out_lvl, int N) {
    int t = blockIdx.x * blockDim.x + threadIdx.x;
    int n = t >> 3;
    int k = t & 7;
    if (n >= N) return;
    int i = n * KDIM + k;
    float l = levels[i];
    float es = __expf(TEMP * l - MSHIFT);
    float den = es, lv = es * l;
    float4 q0 = node_q[i];
    float aw = es * q0.x, ax = es * q0.y, ay = es * q0.z, az = es * q0.w;
    int beg = offs[n], end = offs[n + 1];
#pragma unroll 2
    for (int j = beg; j < end; j++) {
        float4 r = payload[2 * j];
        float4 m = payload[2 * j + 1];
        float tw = m.x;
        int src8 = __float_as_int(m.y);
        float ls = levels[src8 + k];
        float ex = __expf(tw * ls - MSHIFT);
        float4 q = node_q[src8 + k];
        den += ex;
        lv += ex * ls;
        aw += ex * (r.x * q.x - r.y * q.y - r.z * q.z - r.w * q.w);
        ax += ex * (r.x * q.y + r.y * q.x + r.z * q.w - r.w * q.z);
        ay += ex * (r.x * q.z - r.y * q.w + r.z * q.x + r.w * q.y);
        az += ex * (r.x * q.w + r.y * q.z - r.z * q.y + r.w * q.x);
    }
    float inv = 1.0f / den;
    lv *= inv; aw *= inv; ax *= inv; ay *= inv; az *= inv;
    float nn = sqrtf(aw * aw + ax * ax + ay * ay + az * az);
    nn = fmaxf(nn, 1e-12f);
    float rn = 1.0f / nn;
    float4 o;
    o.x = aw * rn; o.y = ax * rn; o.z = ay * rn; o.w = az * rn;
    out_q[i] = o;
    out_lvl[i] = lv;
}

extern "C" void kernel_launch(void* const* d_in, const int* in_sizes, int n_in,
                              void* d_out, int out_size, void* d_ws, size_t ws_size,
                              hipStream_t stream) {
    const float*  levels = (const float*)d_in[0];   // [N,K]
    const float4* node_q = (const float4*)d_in[1];  // [N,K,4]
    const float4* rel_q  = (const float4*)d_in[2];  // [E,4]
    const float*  ew     = (const float*)d_in[3];   // [E]
    const int*    esrc   = (const int*)d_in[4];     // [E]
    const int*    edst   = (const int*)d_in[5];     // [E]

    const int NK = in_sizes[0];
    const int E  = in_sizes[3];
    const int N  = NK / KDIM;
    const int B  = 256;
    const int gE = (E + B - 1) / B;
    const int gN = (NK + B - 1) / B;

    float* out_q   = (float*)d_out;
    float* out_lvl = (float*)d_out + (size_t)NK * 4;

    // ---- primary layout: ghist|gbase|gcursor|deg|offs|qltab|dib|ebuf|payload ----
    const int NBKT = (N + BKT_NODES - 1) >> BKT_SHIFT;
    const int HB   = (E + EPB_H - 1) / EPB_H;
    auto al = [](size_t x) { return (x + 255) & ~(size_t)255; };
    size_t o_ghist = 0;
    size_t o_gbase = o_ghist + al((size_t)MAXNB * 4);
    size_t o_gcur  = o_gbase + al((size_t)(MAXNB + 1) * 4);
    size_t o_deg   = o_gcur  + al((size_t)MAXNB * 4);
    size_t o_offs  = o_deg   + al((size_t)N * 4);
    size_t o_qltab = o_offs  + al((size_t)N * 4);
    size_t o_dib   = o_qltab + al((size_t)NK * 8);
    size_t o_ebuf  = o_dib   + al((size_t)E);
    size_t o_pay   = o_ebuf  + al((size_t)E * 16);
    size_t need    = o_pay   + al((size_t)E * 16);

    if (NBKT <= MAXNB && ws_size >= need) {
        int* ghist   = (int*)((char*)d_ws + o_ghist);
        int* gbase   = (int*)((char*)d_ws + o_gbase);
        int* gcursor = (int*)((char*)d_ws + o_gcur);
        int* deg     = (int*)((char*)d_ws + o_deg);
        int* offs    = (int*)((char*)d_ws + o_offs);
        unsigned long long* qltab = (unsigned long long*)((char*)d_ws + o_qltab);
        unsigned char* dib = (unsigned char*)((char*)d_ws + o_dib);
        float4* ebuf    = (float4*)((char*)d_ws + o_ebuf);
        float4* payload = (float4*)((char*)d_ws + o_pay);

        (void)hipMemsetAsync(ghist, 0, (size_t)MAXNB * 4, stream);
        prep_hist<<<gN + HB, B, 0, stream>>>(levels, node_q, qltab, NK, gN,
                                             edst, ghist, E);
        scan_buckets<<<1, 1024, 0, stream>>>(ghist, gbase, gcursor, NBKT, E);
        int PB = (E + TILE - 1) / TILE;
        partition_lds<<<PB, PTHR, 0, stream>>>(edst, esrc, ew, rel_q, gcursor,
                                               ebuf, dib, E);
        fine_lds<<<NBKT, B, 0, stream>>>(gbase, ebuf, dib, payload, deg, offs, N);
        int gW = (int)(((size_t)N * 64 + B - 1) / B);   // one wave64 per node
        agg_wave<<<gW, B, 0, stream>>>(levels, node_q, qltab, deg, offs,
                                       payload, (float4*)out_q, out_lvl, N);
        return;
    }

    // ---- fallback: round-3 CSR pipeline ----
    const int nb = (N + 255) / 256;
    int* deg  = (int*)d_ws;
    int* offs = deg + N;
    int* bsum = offs + N + 1;
    size_t prefix = (size_t)(2 * N + 1 + nb);
    int* rank = bsum + nb;
    size_t pay_off = (prefix + E + 3) & ~(size_t)3;
    float4* payload = (float4*)((int*)d_ws + pay_off);

    (void)hipMemsetAsync(deg, 0, (size_t)N * sizeof(int), stream);
    rank_kernel<<<gE, B, 0, stream>>>(edst, deg, rank, E);
    scan1<<<nb, 256, 0, stream>>>(deg, offs, bsum, N);
    scan2<<<1, 1024, 0, stream>>>(bsum, nb);
    scan3<<<nb, 256, 0, stream>>>(offs, bsum, N, E);
    permute_kernel<<<gE, B, 0, stream>>>(edst, rank, offs, rel_q, ew, esrc,
                                         payload, E);
    agg_payload<<<gN, B, 0, stream>>>(levels, node_q, offs, payload,
                                      (float4*)out_q, out_lvl, N);
}